// Round 2
// baseline (337.601 us; speedup 1.0000x reference)
//
#include <hip/hip_runtime.h>
#include <hip/hip_bf16.h>
#include <stdint.h>

// Problem dims (fixed by reference)
#define BB 8
#define NN 8192
#define DD 512
#define HH 8
#define DHD 64

typedef __attribute__((ext_vector_type(8))) short bf16x8;
typedef __attribute__((ext_vector_type(4))) float f32x4;

__device__ __forceinline__ unsigned short f2bf(float f) {
  union { float f; unsigned int u; } v; v.f = f;
  return (unsigned short)((v.u + 0x7FFFu + ((v.u >> 16) & 1u)) >> 16);
}

__device__ __forceinline__ void async16(const void* g, void* l) {
  __builtin_amdgcn_global_load_lds(
      (const __attribute__((address_space(1))) void*)g,
      (__attribute__((address_space(3))) void*)l, 16, 0, 0);
}

// ---------------- Kernel 1: RoPE + cast to bf16 ----------------
// x[d<256] = h[d]*cos[d] - h[d+256]*sin[d]; x[d>=256] = h[d]*cos[d] + h[d-256]*sin[d]
// Launch with `rows` rows (h/x pre-offset to the batch if per-batch path).
__global__ void rope_kernel(const float* __restrict__ h, const float* __restrict__ cs,
                            const float* __restrict__ sn, unsigned short* __restrict__ x) {
  int t = blockIdx.x * 256 + threadIdx.x;
  int r = t >> 6;                           // row index (b*N+n or n)
  int c = (t & 63) << 2;                    // d in [0,256), 4 at a time
  int n = r & (NN - 1);
  size_t base  = (size_t)r * DD + c;
  size_t tbase = (size_t)n * DD + c;
  float4 h1 = *(const float4*)(h + base);
  float4 h2 = *(const float4*)(h + base + 256);
  float4 c1 = *(const float4*)(cs + tbase);
  float4 c2 = *(const float4*)(cs + tbase + 256);
  float4 s1 = *(const float4*)(sn + tbase);
  float4 s2 = *(const float4*)(sn + tbase + 256);
  float4 x1, x2;
  x1.x = h1.x * c1.x - h2.x * s1.x;  x2.x = h2.x * c2.x + h1.x * s2.x;
  x1.y = h1.y * c1.y - h2.y * s1.y;  x2.y = h2.y * c2.y + h1.y * s2.y;
  x1.z = h1.z * c1.z - h2.z * s1.z;  x2.z = h2.z * c2.z + h1.z * s2.z;
  x1.w = h1.w * c1.w - h2.w * s1.w;  x2.w = h2.w * c2.w + h1.w * s2.w;
  uint2 p1, p2;
  p1.x = (unsigned)f2bf(x1.x) | ((unsigned)f2bf(x1.y) << 16);
  p1.y = (unsigned)f2bf(x1.z) | ((unsigned)f2bf(x1.w) << 16);
  p2.x = (unsigned)f2bf(x2.x) | ((unsigned)f2bf(x2.y) << 16);
  p2.y = (unsigned)f2bf(x2.z) | ((unsigned)f2bf(x2.w) << 16);
  *(uint2*)(x + base)       = p1;
  *(uint2*)(x + base + 256) = p2;
}

// ---------------- Kernel 2: kv[bh] = X_h^T X_h (64x64, fp32 atomic accumulate) ----
// grid (#bh, nchunks), block 256 (4 waves; each wave one 32x32 quadrant).
// rows per chunk = NN / gridDim.y. x/kv may be pre-offset to a batch (then bh = h).
__global__ void kv_kernel(const unsigned short* __restrict__ x, float* __restrict__ kv) {
  __shared__ __align__(16) unsigned short xt[64 * 72];  // transposed [d][n], pad row to 72
  int bh = blockIdx.x;
  int b = bh >> 3, hh = bh & 7;
  int chunk = blockIdx.y;
  int rows_per_chunk = NN / gridDim.y;
  int tiles = rows_per_chunk >> 6;
  int tid = threadIdx.x;
  int wave = tid >> 6, lane = tid & 63;
  int d0 = (wave & 1) * 32, e0 = (wave >> 1) * 32;
  int l15 = lane & 15, q = lane >> 4;
  f32x4 acc[2][2];
#pragma unroll
  for (int i = 0; i < 2; ++i)
#pragma unroll
    for (int j = 0; j < 2; ++j) acc[i][j] = (f32x4){0.f, 0.f, 0.f, 0.f};

  int nrow = tid >> 2;                   // 0..63
  int cseg = (tid & 3) * 16;             // 0/16/32/48
  const unsigned short* srcbase = x + (size_t)b * NN * DD + hh * DHD + cseg;

  for (int t = 0; t < tiles; ++t) {
    int n0 = chunk * rows_per_chunk + t * 64;
    const unsigned short* src = srcbase + (size_t)(n0 + nrow) * DD;
    uint4 p0 = *(const uint4*)(src);
    uint4 p1 = *(const uint4*)(src + 8);
    unsigned short v[16];
    *(uint4*)&v[0] = p0;  *(uint4*)&v[8] = p1;
#pragma unroll
    for (int j = 0; j < 16; ++j) xt[(cseg + j) * 72 + nrow] = v[j];
    __syncthreads();
#pragma unroll
    for (int ks = 0; ks < 64; ks += 32) {
      bf16x8 a0 = *(const bf16x8*)&xt[(d0 + l15) * 72 + ks + q * 8];
      bf16x8 a1 = *(const bf16x8*)&xt[(d0 + 16 + l15) * 72 + ks + q * 8];
      bf16x8 b0 = *(const bf16x8*)&xt[(e0 + l15) * 72 + ks + q * 8];
      bf16x8 b1 = *(const bf16x8*)&xt[(e0 + 16 + l15) * 72 + ks + q * 8];
      acc[0][0] = __builtin_amdgcn_mfma_f32_16x16x32_bf16(a0, b0, acc[0][0], 0, 0, 0);
      acc[1][0] = __builtin_amdgcn_mfma_f32_16x16x32_bf16(a1, b0, acc[1][0], 0, 0, 0);
      acc[0][1] = __builtin_amdgcn_mfma_f32_16x16x32_bf16(a0, b1, acc[0][1], 0, 0, 0);
      acc[1][1] = __builtin_amdgcn_mfma_f32_16x16x32_bf16(a1, b1, acc[1][1], 0, 0, 0);
    }
    __syncthreads();
  }
  float* dst = kv + (size_t)bh * 4096;
#pragma unroll
  for (int i = 0; i < 2; ++i)
#pragma unroll
    for (int j = 0; j < 2; ++j) {
      int col = e0 + j * 16 + l15;
#pragma unroll
      for (int reg = 0; reg < 4; ++reg) {
        int row = d0 + i * 16 + q * 4 + reg;   // C/D layout: col=lane&15, row=quad*4+reg
        atomicAdd(&dst[row * 64 + col], acc[i][j][reg]);
      }
    }
}

// ---------------- Kernel 3: WkvT[bh][c=h*64+e][f] = sum_d W[h*64+d][f] * kv[bh,d,e] ----
// grid (#bh, 4 f-chunks of 128), block 256. kv/wkvt may be pre-offset to a batch.
__global__ void wkvt_kernel(const float* __restrict__ W, const float* __restrict__ kv,
                            unsigned short* __restrict__ wkvt) {
  __shared__ float kvs[4096];     // kv[bh] 64x64
  __shared__ float ws[8192];      // W chunk [64 d][128 f]
  int bh = blockIdx.x, fc = blockIdx.y;
  int b = bh >> 3, hh = bh & 7;
  int f0 = fc * 128;
  int tid = threadIdx.x;
#pragma unroll
  for (int i = 0; i < 4; ++i) {
    int idx = i * 1024 + tid * 4;
    *(float4*)&kvs[idx] = *(const float4*)&kv[(size_t)bh * 4096 + idx];
  }
#pragma unroll
  for (int i = 0; i < 8; ++i) {
    int idx = i * 1024 + tid * 4;
    int d = idx >> 7, f = idx & 127;
    *(float4*)&ws[idx] = *(const float4*)&W[(size_t)(hh * DHD + d) * DD + f0 + f];
  }
  __syncthreads();
  int e = tid & 63, fg = tid >> 6;  // each thread: one e, 32 f values
  float acc[32];
#pragma unroll
  for (int j = 0; j < 32; ++j) acc[j] = 0.f;
  for (int d = 0; d < 64; ++d) {
    float kvv = kvs[d * 64 + e];
    const float* wr = &ws[d * 128 + fg * 32];
#pragma unroll
    for (int j = 0; j < 32; ++j) acc[j] = fmaf(wr[j], kvv, acc[j]);
  }
  unsigned short tmp[32];
#pragma unroll
  for (int j = 0; j < 32; ++j) tmp[j] = f2bf(acc[j]);
  size_t obase = ((size_t)(b * DD + hh * DHD + e)) * DD + f0 + fg * 32;
#pragma unroll
  for (int qq = 0; qq < 4; ++qq)
    *(uint4*)&wkvt[obase + qq * 8] = *(uint4*)&tmp[qq * 8];
}

// ---------------- Kernel 4: out[b] = x_b [8192x512] @ WkvT_b^T  (bf16 MFMA, fp32 out) ----
// grid (64 m-tiles, 4 c-tiles, nb), block 256 (4 waves; wave tile 64x64 = 4x4 of 16x16)
__global__ __launch_bounds__(256) void gemm_kernel(const unsigned short* __restrict__ x,
                                                   const unsigned short* __restrict__ wkvt,
                                                   float* __restrict__ out) {
  __shared__ __align__(16) unsigned short As[128 * 64];  // [m][k]
  __shared__ __align__(16) unsigned short Bs[128 * 64];  // [c][k]
  int mt = blockIdx.x, ct = blockIdx.y, bz = blockIdx.z;
  int tid = threadIdx.x, wave = tid >> 6, lane = tid & 63;
  int m_off = (wave & 1) * 64, c_off = (wave >> 1) * 64;
  int l15 = lane & 15, q = lane >> 4;
  int lrow = lane >> 3, lcol = (lane & 7) * 8;
  const unsigned short* Ag = x    + ((size_t)bz * NN + mt * 128) * DD;
  const unsigned short* Bg = wkvt + ((size_t)bz * DD + ct * 128) * DD;
  f32x4 acc[4][4];
#pragma unroll
  for (int i = 0; i < 4; ++i)
#pragma unroll
    for (int j = 0; j < 4; ++j) acc[i][j] = (f32x4){0.f, 0.f, 0.f, 0.f};

  for (int kk = 0; kk < 512; kk += 64) {
#pragma unroll
    for (int i = 0; i < 4; ++i) {
      int r = wave * 32 + i * 8 + lrow;
      async16(Ag + (size_t)r * DD + kk + lcol, &As[(wave * 32 + i * 8) * 64]);
      async16(Bg + (size_t)r * DD + kk + lcol, &Bs[(wave * 32 + i * 8) * 64]);
    }
    __syncthreads();
#pragma unroll
    for (int ks = 0; ks < 64; ks += 32) {
      bf16x8 a[4], bb[4];
#pragma unroll
      for (int i = 0; i < 4; ++i)
        a[i] = *(const bf16x8*)&As[(m_off + i * 16 + l15) * 64 + ks + q * 8];
#pragma unroll
      for (int j = 0; j < 4; ++j)
        bb[j] = *(const bf16x8*)&Bs[(c_off + j * 16 + l15) * 64 + ks + q * 8];
#pragma unroll
      for (int i = 0; i < 4; ++i)
#pragma unroll
        for (int j = 0; j < 4; ++j)
          acc[i][j] = __builtin_amdgcn_mfma_f32_16x16x32_bf16(a[i], bb[j], acc[i][j], 0, 0, 0);
    }
    __syncthreads();
  }
  float* ob = out + ((size_t)bz * NN + mt * 128) * DD + ct * 128;
#pragma unroll
  for (int i = 0; i < 4; ++i)
#pragma unroll
    for (int j = 0; j < 4; ++j) {
      int row = m_off + i * 16 + q * 4;
      int col = c_off + j * 16 + l15;
#pragma unroll
      for (int reg = 0; reg < 4; ++reg)
        ob[(size_t)(row + reg) * DD + col] = acc[i][j][reg];
    }
}

extern "C" void kernel_launch(void* const* d_in, const int* in_sizes, int n_in,
                              void* d_out, int out_size, void* d_ws, size_t ws_size,
                              hipStream_t stream) {
  (void)in_sizes; (void)n_in; (void)out_size;
  const float* h  = (const float*)d_in[0];
  const float* W  = (const float*)d_in[1];
  const float* cs = (const float*)d_in[2];
  const float* sn = (const float*)d_in[3];
  float* out = (float*)d_out;

  const size_t x_full     = (size_t)BB * NN * DD * 2;        // 67.1 MB
  const size_t kv_full    = (size_t)BB * HH * DHD * DHD * 4; // 1.0 MB
  const size_t wkvt_full  = (size_t)BB * DD * DD * 2;        // 4.2 MB
  const size_t x_batch    = (size_t)NN * DD * 2;             // 8.4 MB
  const size_t kv_batch   = (size_t)HH * DHD * DHD * 4;      // 131 KB
  const size_t wkvt_batch = (size_t)DD * DD * 2;             // 524 KB

  if (ws_size >= x_full + kv_full + wkvt_full) {
    // -------- full path: 4 launches, maximal per-kernel utilization --------
    unsigned short* xw   = (unsigned short*)d_ws;
    float*          kv   = (float*)((char*)d_ws + x_full);
    unsigned short* wkvt = (unsigned short*)((char*)d_ws + x_full + kv_full);
    hipMemsetAsync(kv, 0, kv_full, stream);
    rope_kernel<<<dim3(BB * NN * 64 / 256), dim3(256), 0, stream>>>(h, cs, sn, xw);
    kv_kernel<<<dim3(BB * HH, 8), dim3(256), 0, stream>>>(xw, kv);
    wkvt_kernel<<<dim3(BB * HH, 4), dim3(256), 0, stream>>>(W, kv, wkvt);
    gemm_kernel<<<dim3(NN / 128, DD / 128, BB), dim3(256), 0, stream>>>(xw, wkvt, out);
  } else {
    // -------- per-batch fallback: ~9.1 MB workspace, 33 launches --------
    unsigned short* xw   = (unsigned short*)d_ws;
    float*          kv   = (float*)((char*)d_ws + x_batch);
    unsigned short* wkvt = (unsigned short*)((char*)d_ws + x_batch + kv_batch);
    for (int b = 0; b < BB; ++b) {
      hipMemsetAsync(kv, 0, kv_batch, stream);
      rope_kernel<<<dim3(NN * 64 / 256), dim3(256), 0, stream>>>(
          h + (size_t)b * NN * DD, cs, sn, xw);
      kv_kernel<<<dim3(HH, 32), dim3(256), 0, stream>>>(xw, kv);
      wkvt_kernel<<<dim3(HH, 4), dim3(256), 0, stream>>>(W, kv, wkvt);
      gemm_kernel<<<dim3(NN / 128, DD / 128, 1), dim3(256), 0, stream>>>(
          xw, wkvt, out + (size_t)b * NN * DD);
    }
  }
}

// Round 3
// 334.274 us; speedup vs baseline: 1.0100x; 1.0100x over previous
//
#include <hip/hip_runtime.h>
#include <hip/hip_bf16.h>
#include <stdint.h>

// Problem dims (fixed by reference)
#define BB 8
#define NN 8192
#define DD 512
#define HH 8
#define DHD 64
#define NCH 16   // kv partial chunks (each = 512 rows = 8 tiles of 64)

typedef __attribute__((ext_vector_type(8))) short bf16x8;
typedef __attribute__((ext_vector_type(4))) float f32x4;
typedef __attribute__((ext_vector_type(4))) float f4v;

__device__ __forceinline__ unsigned short f2bf(float f) {
  union { float f; unsigned int u; } v; v.f = f;
  return (unsigned short)((v.u + 0x7FFFu + ((v.u >> 16) & 1u)) >> 16);
}

__device__ __forceinline__ void async16(const void* g, void* l) {
  __builtin_amdgcn_global_load_lds(
      (const __attribute__((address_space(1))) void*)g,
      (__attribute__((address_space(3))) void*)l, 16, 0, 0);
}

// ---------------- Kernel 1: RoPE + cast to bf16 ----------------
// x[d<256] = h[d]*cos[d] - h[d+256]*sin[d]; x[d>=256] = h[d]*cos[d] + h[d-256]*sin[d]
__global__ void rope_kernel(const float* __restrict__ h, const float* __restrict__ cs,
                            const float* __restrict__ sn, unsigned short* __restrict__ x) {
  int t = blockIdx.x * 256 + threadIdx.x;
  int r = t >> 6;                           // row index (b*N+n or n)
  int c = (t & 63) << 2;                    // d in [0,256), 4 at a time
  int n = r & (NN - 1);
  size_t base  = (size_t)r * DD + c;
  size_t tbase = (size_t)n * DD + c;
  // h is read exactly once -> nontemporal (don't thrash L2 against poison eviction)
  f4v h1 = __builtin_nontemporal_load((const f4v*)(h + base));
  f4v h2 = __builtin_nontemporal_load((const f4v*)(h + base + 256));
  f4v c1 = *(const f4v*)(cs + tbase);
  f4v c2 = *(const f4v*)(cs + tbase + 256);
  f4v s1 = *(const f4v*)(sn + tbase);
  f4v s2 = *(const f4v*)(sn + tbase + 256);
  f4v x1 = h1 * c1 - h2 * s1;
  f4v x2 = h2 * c2 + h1 * s2;
  uint2 p1, p2;
  p1.x = (unsigned)f2bf(x1.x) | ((unsigned)f2bf(x1.y) << 16);
  p1.y = (unsigned)f2bf(x1.z) | ((unsigned)f2bf(x1.w) << 16);
  p2.x = (unsigned)f2bf(x2.x) | ((unsigned)f2bf(x2.y) << 16);
  p2.y = (unsigned)f2bf(x2.z) | ((unsigned)f2bf(x2.w) << 16);
  *(uint2*)(x + base)       = p1;
  *(uint2*)(x + base + 256) = p2;
}

// ---------------- Kernel 2: kv partials, kvp[chunk][bh] = X_h^T X_h over 512 rows ----
// grid (#bh, NCH), block 256 (4 waves; each wave one 32x32 quadrant of the 64x64 result).
// Transpose via paired-b32 LDS writes, pitch 68 (exact 2-way bank aliasing = free).
__global__ void kv_kernel(const unsigned short* __restrict__ x, float* __restrict__ kvp) {
  __shared__ __align__(16) unsigned short xt[64 * 68];  // [d][n], pitch 68
  int bh = blockIdx.x;
  int b = bh >> 3, hh = bh & 7;
  int chunk = blockIdx.y;
  int tid = threadIdx.x;
  int wave = tid >> 6, lane = tid & 63;
  int d0 = (wave & 1) * 32, e0 = (wave >> 1) * 32;
  int l15 = lane & 15, q = lane >> 4;
  f32x4 acc[2][2];
#pragma unroll
  for (int i = 0; i < 2; ++i)
#pragma unroll
    for (int j = 0; j < 2; ++j) acc[i][j] = (f32x4){0.f, 0.f, 0.f, 0.f};

  int rp  = tid & 31;    // row-pair: rows 2rp, 2rp+1
  int seg = tid >> 5;    // d-segment: cols seg*8 .. seg*8+7
  const unsigned short* srcbase = x + (size_t)b * NN * DD + hh * DHD + seg * 8;

  for (int t = 0; t < 8; ++t) {          // 8 tiles of 64 rows = 512 rows/chunk
    int n0 = chunk * 512 + t * 64;
    const unsigned short* s0 = srcbase + (size_t)(n0 + 2 * rp) * DD;
    uint4 p0 = *(const uint4*)(s0);
    uint4 p1 = *(const uint4*)(s0 + DD);
    unsigned short a0[8], a1[8];
    *(uint4*)a0 = p0;  *(uint4*)a1 = p1;
    __syncthreads();                     // prior tile's MFMA reads done before overwrite
#pragma unroll
    for (int j = 0; j < 8; ++j) {
      unsigned pack = (unsigned)a0[j] | ((unsigned)a1[j] << 16);
      ((unsigned*)xt)[(seg * 8 + j) * 34 + rp] = pack;   // elem (d)*68 + 2rp
    }
    __syncthreads();
#pragma unroll
    for (int ks = 0; ks < 64; ks += 32) {
      bf16x8 a0f = *(const bf16x8*)&xt[(d0 + l15) * 68 + ks + q * 8];
      bf16x8 a1f = *(const bf16x8*)&xt[(d0 + 16 + l15) * 68 + ks + q * 8];
      bf16x8 b0f = *(const bf16x8*)&xt[(e0 + l15) * 68 + ks + q * 8];
      bf16x8 b1f = *(const bf16x8*)&xt[(e0 + 16 + l15) * 68 + ks + q * 8];
      acc[0][0] = __builtin_amdgcn_mfma_f32_16x16x32_bf16(a0f, b0f, acc[0][0], 0, 0, 0);
      acc[1][0] = __builtin_amdgcn_mfma_f32_16x16x32_bf16(a1f, b0f, acc[1][0], 0, 0, 0);
      acc[0][1] = __builtin_amdgcn_mfma_f32_16x16x32_bf16(a0f, b1f, acc[0][1], 0, 0, 0);
      acc[1][1] = __builtin_amdgcn_mfma_f32_16x16x32_bf16(a1f, b1f, acc[1][1], 0, 0, 0);
    }
  }
  float* dst = kvp + ((size_t)chunk * gridDim.x + bh) * 4096;
#pragma unroll
  for (int i = 0; i < 2; ++i)
#pragma unroll
    for (int j = 0; j < 2; ++j) {
      int col = e0 + j * 16 + l15;
#pragma unroll
      for (int reg = 0; reg < 4; ++reg) {
        int row = d0 + i * 16 + q * 4 + reg;   // C/D: col=lane&15, row=quad*4+reg
        dst[row * 64 + col] = acc[i][j][reg];  // non-atomic partial store
      }
    }
}

// ---------------- Kernel 3: sum kv partials, then WkvT[bh][e][f] = sum_d W[h*64+d][f]*kv[d][e]
// grid (#bh, 4 f-chunks of 128), block 256.
__global__ void wkvt_kernel(const float* __restrict__ W, const float* __restrict__ kvp,
                            unsigned short* __restrict__ wkvt) {
  __shared__ float kvs[4096];     // kv[bh] 64x64 (summed)
  __shared__ float ws[8192];      // W chunk [64 d][128 f]
  int bh = blockIdx.x, fc = blockIdx.y;
  int nbh = gridDim.x;
  int b = bh >> 3, hh = bh & 7;
  int f0 = fc * 128;
  int tid = threadIdx.x;
#pragma unroll
  for (int i = 0; i < 4; ++i) {
    int idx = i * 1024 + tid * 4;
    f4v s = (f4v){0.f, 0.f, 0.f, 0.f};
    for (int c = 0; c < NCH; ++c)
      s += *(const f4v*)&kvp[((size_t)c * nbh + bh) * 4096 + idx];
    *(f4v*)&kvs[idx] = s;
  }
#pragma unroll
  for (int i = 0; i < 8; ++i) {
    int idx = i * 1024 + tid * 4;
    int d = idx >> 7, f = idx & 127;
    *(float4*)&ws[idx] = *(const float4*)&W[(size_t)(hh * DHD + d) * DD + f0 + f];
  }
  __syncthreads();
  int e = tid & 63, fg = tid >> 6;  // each thread: one e, 32 f values
  float acc[32];
#pragma unroll
  for (int j = 0; j < 32; ++j) acc[j] = 0.f;
  for (int d = 0; d < 64; ++d) {
    float kvv = kvs[d * 64 + e];
    const float* wr = &ws[d * 128 + fg * 32];
#pragma unroll
    for (int j = 0; j < 32; ++j) acc[j] = fmaf(wr[j], kvv, acc[j]);
  }
  unsigned short tmp[32];
#pragma unroll
  for (int j = 0; j < 32; ++j) tmp[j] = f2bf(acc[j]);
  size_t obase = ((size_t)(b * DD + hh * DHD + e)) * DD + f0 + fg * 32;
#pragma unroll
  for (int qq = 0; qq < 4; ++qq)
    *(uint4*)&wkvt[obase + qq * 8] = *(uint4*)&tmp[qq * 8];
}

// ---------------- Kernel 4: out[b] = x_b [8192x512] @ WkvT_b^T  (bf16 MFMA, fp32 out) ----
// 128x256 block tile, 4 waves each 64x128 (4x8 of 16x16). grid (64, 2, nb).
__global__ __launch_bounds__(256, 2) void gemm_kernel(const unsigned short* __restrict__ x,
                                                      const unsigned short* __restrict__ wkvt,
                                                      float* __restrict__ out) {
  __shared__ __align__(16) unsigned short As[128 * 64];  // [m][k] 16 KB
  __shared__ __align__(16) unsigned short Bs[256 * 64];  // [c][k] 32 KB
  int mt = blockIdx.x, ct = blockIdx.y, bz = blockIdx.z;
  int tid = threadIdx.x, wave = tid >> 6, lane = tid & 63;
  int m_off = (wave & 1) * 64, c_off = (wave >> 1) * 128;
  int l15 = lane & 15, q = lane >> 4;
  int lrow = lane >> 3, lcol = (lane & 7) * 8;
  const unsigned short* Ag = x    + ((size_t)bz * NN + mt * 128) * DD;
  const unsigned short* Bg = wkvt + ((size_t)bz * DD + ct * 256) * DD;
  f32x4 acc[4][8];
#pragma unroll
  for (int i = 0; i < 4; ++i)
#pragma unroll
    for (int j = 0; j < 8; ++j) acc[i][j] = (f32x4){0.f, 0.f, 0.f, 0.f};

  for (int kk = 0; kk < 512; kk += 64) {
#pragma unroll
    for (int i = 0; i < 4; ++i)
      async16(Ag + (size_t)(wave * 32 + i * 8 + lrow) * DD + kk + lcol,
              &As[(wave * 32 + i * 8) * 64]);
#pragma unroll
    for (int i = 0; i < 8; ++i)
      async16(Bg + (size_t)(wave * 64 + i * 8 + lrow) * DD + kk + lcol,
              &Bs[(wave * 64 + i * 8) * 64]);
    __syncthreads();
#pragma unroll
    for (int ks = 0; ks < 64; ks += 32) {
      bf16x8 a[4], bb[8];
#pragma unroll
      for (int i = 0; i < 4; ++i)
        a[i] = *(const bf16x8*)&As[(m_off + i * 16 + l15) * 64 + ks + q * 8];
#pragma unroll
      for (int j = 0; j < 8; ++j)
        bb[j] = *(const bf16x8*)&Bs[(c_off + j * 16 + l15) * 64 + ks + q * 8];
#pragma unroll
      for (int i = 0; i < 4; ++i)
#pragma unroll
        for (int j = 0; j < 8; ++j)
          acc[i][j] = __builtin_amdgcn_mfma_f32_16x16x32_bf16(a[i], bb[j], acc[i][j], 0, 0, 0);
    }
    __syncthreads();
  }
  float* ob = out + ((size_t)bz * NN + mt * 128) * DD + ct * 256;
#pragma unroll
  for (int i = 0; i < 4; ++i)
#pragma unroll
    for (int j = 0; j < 8; ++j) {
      int row = m_off + i * 16 + q * 4;
      int col = c_off + j * 16 + l15;
#pragma unroll
      for (int reg = 0; reg < 4; ++reg)
        ob[(size_t)(row + reg) * DD + col] = acc[i][j][reg];
    }
}

extern "C" void kernel_launch(void* const* d_in, const int* in_sizes, int n_in,
                              void* d_out, int out_size, void* d_ws, size_t ws_size,
                              hipStream_t stream) {
  (void)in_sizes; (void)n_in; (void)out_size;
  const float* h  = (const float*)d_in[0];
  const float* W  = (const float*)d_in[1];
  const float* cs = (const float*)d_in[2];
  const float* sn = (const float*)d_in[3];
  float* out = (float*)d_out;

  const size_t x_full     = (size_t)BB * NN * DD * 2;              // 67.1 MB
  const size_t kvp_full   = (size_t)NCH * BB * HH * DHD * DHD * 4; // 16.8 MB
  const size_t wkvt_full  = (size_t)BB * DD * DD * 2;              // 4.2 MB
  const size_t x_batch    = (size_t)NN * DD * 2;                   // 8.4 MB
  const size_t kvp_batch  = (size_t)NCH * HH * DHD * DHD * 4;      // 2.1 MB
  const size_t wkvt_batch = (size_t)DD * DD * 2;                   // 524 KB

  if (ws_size >= x_full + kvp_full + wkvt_full) {
    // -------- full path: 4 launches --------
    unsigned short* xw   = (unsigned short*)d_ws;
    float*          kvp  = (float*)((char*)d_ws + x_full);
    unsigned short* wkvt = (unsigned short*)((char*)d_ws + x_full + kvp_full);
    rope_kernel<<<dim3(BB * NN * 64 / 256), dim3(256), 0, stream>>>(h, cs, sn, xw);
    kv_kernel<<<dim3(BB * HH, NCH), dim3(256), 0, stream>>>(xw, kvp);
    wkvt_kernel<<<dim3(BB * HH, 4), dim3(256), 0, stream>>>(W, kvp, wkvt);
    gemm_kernel<<<dim3(NN / 128, DD / 256, BB), dim3(256), 0, stream>>>(xw, wkvt, out);
  } else {
    // -------- per-batch fallback (~11 MB workspace) --------
    unsigned short* xw   = (unsigned short*)d_ws;
    float*          kvp  = (float*)((char*)d_ws + x_batch);
    unsigned short* wkvt = (unsigned short*)((char*)d_ws + x_batch + kvp_batch);
    for (int b = 0; b < BB; ++b) {
      rope_kernel<<<dim3(NN * 64 / 256), dim3(256), 0, stream>>>(
          h + (size_t)b * NN * DD, cs, sn, xw);
      kv_kernel<<<dim3(HH, NCH), dim3(256), 0, stream>>>(xw, kvp);
      wkvt_kernel<<<dim3(HH, 4), dim3(256), 0, stream>>>(W, kvp, wkvt);
      gemm_kernel<<<dim3(NN / 128, DD / 256, 1), dim3(256), 0, stream>>>(
          xw, wkvt, out + (size_t)b * NN * DD);
    }
  }
}